// Round 3
// baseline (316.768 us; speedup 1.0000x reference)
//
#include <hip/hip_runtime.h>
#include <hip/hip_fp16.h>

#define BHW   25088
#define HW    3136
#define DD    64
#define KNEG  100
#define NBLK2 (BHW / 4)   // 6272 blocks, 4 waves (n's) per block

typedef _Float16 f16x2 __attribute__((ext_vector_type(2)));

#if __has_builtin(__builtin_amdgcn_fdot2)
#define HAVE_FDOT2 1
#else
#define HAVE_FDOT2 0
#endif

__device__ __forceinline__ float dot2f(f16x2 a, f16x2 b, float acc) {
#if HAVE_FDOT2
    return __builtin_amdgcn_fdot2(a, b, acc, false);   // v_dot2_f32_f16
#else
    return acc + (float)a.x * (float)b.x + (float)a.y * (float)b.y;
#endif
}

__device__ __forceinline__ f16x2 bc(float f) {
    union { float f; f16x2 h; } u; u.f = f; return u.h;
}

// ---------------------------------------------------------------------------
// Kernel 1: normalize x1 rows -> xh (fp16, row-major (n,64)), positive[n] in
// f32. LDS tile-transpose so d-major global reads and n-major writes are both
// coalesced. All 256 threads active in the norm/pos phase.
// ---------------------------------------------------------------------------
__global__ __launch_bounds__(256) void k1_normalize(
    const float* __restrict__ x1, const float* __restrict__ x2,
    f16x2* __restrict__ xh, float* __restrict__ pos)
{
    __shared__ float A[64][65];   // +1 pad: conflict-free column reads
    __shared__ float C[64][65];
    __shared__ float inv1[64];

    const int t   = threadIdx.x;
    const int col = t & 63;       // hw within tile
    const int qr  = t >> 6;       // wave id 0..3
    const int b    = blockIdx.x / 49;
    const int tile = blockIdx.x % 49;
    const int hw0  = tile * 64;

    const float* p1 = x1 + (size_t)b * DD * HW + hw0;
    const float* p2 = x2 + (size_t)b * DD * HW + hw0;

#pragma unroll
    for (int i = 0; i < 16; ++i) {
        const int row = i * 4 + qr;                  // d index
        A[row][col] = p1[(size_t)row * HW + col];    // coalesced 256B
        C[row][col] = p2[(size_t)row * HW + col];
    }
    __syncthreads();

    // phase 2: 256 threads = 64 rows x 4 d-chunks of 16
    const int l = t & 63;
    const int r = qr * 16 + (l & 15);   // row (hw) within tile
    const int c = l >> 4;               // d-chunk 0..3

    float na = 0.f, nc = 0.f;
#pragma unroll
    for (int j = 0; j < 16; ++j) {
        const int d = c * 16 + j;
        const float a = A[d][r], cc = C[d][r];
        na += a * a;
        nc += cc * cc;
    }
    na += __shfl_xor(na, 16); na += __shfl_xor(na, 32);
    nc += __shfl_xor(nc, 16); nc += __shfl_xor(nc, 32);
    const float r1 = 1.0f / fmaxf(sqrtf(na), 1e-12f);
    const float rc = 1.0f / fmaxf(sqrtf(nc), 1e-12f);
    const float scale = r1 * rc;

    float p = 0.f;
#pragma unroll
    for (int j = 0; j < 16; ++j) {
        const int d = c * 16 + j;
        p += __expf(A[d][r] * C[d][r] * scale);   // TEMP == 1
    }
    p += __shfl_xor(p, 16); p += __shfl_xor(p, 32);

    if (c == 0) {
        pos[b * HW + hw0 + r] = p;
        inv1[r] = r1;
    }
    __syncthreads();

    // phase 3: write fp16 table row-major. Half-wave (32 lanes) covers one
    // row's 32 half2 -> 128B contiguous per half-wave store.
    f16x2* outh = xh + (size_t)(b * HW + hw0) * 32;
    const int rowsub = t >> 5;    // 0..7
    const int cp = t & 31;        // half2 column 0..31
#pragma unroll
    for (int i = 0; i < 8; ++i) {
        const int nl = i * 8 + rowsub;
        const float s = inv1[nl];
        f16x2 v;
        v.x = (_Float16)(A[2 * cp][nl] * s);
        v.y = (_Float16)(A[2 * cp + 1][nl] * s);
        outh[(size_t)nl * 32 + cp] = v;
    }
}

// ---------------------------------------------------------------------------
// Kernel 2: negative[n] = sum_k exp(dot64(xh[n], xh[idx[n,k]])), then
// loss partial per block, then last-block-done final reduction (replaces k3).
// One wave per n; 4 lanes per negative (g=l>>2), lane c=l&3 reads 32B of the
// gathered fp16 row (2x float4). Table is 3.2MB -> L2-resident per XCD.
// ---------------------------------------------------------------------------
__global__ __launch_bounds__(256) void k2_negative(
    const f16x2* __restrict__ xh, const int* __restrict__ neg_idx,
    const float* __restrict__ pos, float* __restrict__ partials,
    int* __restrict__ cnt, float* __restrict__ out)
{
    __shared__ float wpart[4];
    __shared__ float red[256];
    __shared__ int   lastFlag;

    const int t = threadIdx.x;
    const int w = t >> 6;         // wave id 0..3
    const int l = t & 63;
    const int n = blockIdx.x * 4 + w;
    const int g = l >> 2;         // negative group 0..15
    const int c = l & 3;          // 32B slot within row

    const float4* gp = (const float4*)xh;   // 8 halfs per float4; 8 per row
    const int* idxp = neg_idx + (size_t)n * KNEG;

    // query fragment: halfs [c*16, c*16+16) of row n
    const size_t qb = (size_t)n * 8 + c * 2;
    const float4 qa = gp[qb], qv = gp[qb + 1];
    const f16x2 q0 = bc(qa.x), q1 = bc(qa.y), q2 = bc(qa.z), q3 = bc(qa.w);
    const f16x2 q4 = bc(qv.x), q5 = bc(qv.y), q6 = bc(qv.z), q7 = bc(qv.w);

    float acc = 0.f;
#pragma unroll
    for (int i = 0; i < 7; ++i) {
        const int kidx = i * 16 + g;
        const int kc   = kidx < KNEG ? kidx : (KNEG - 1);  // clamp (masked)
        const int row  = idxp[kc];
        const size_t base = (size_t)row * 8 + c * 2;
        const float4 va = gp[base], vb = gp[base + 1];

        float s = 0.f;
        s = dot2f(bc(va.x), q0, s);
        s = dot2f(bc(va.y), q1, s);
        s = dot2f(bc(va.z), q2, s);
        s = dot2f(bc(va.w), q3, s);
        s = dot2f(bc(vb.x), q4, s);
        s = dot2f(bc(vb.y), q5, s);
        s = dot2f(bc(vb.z), q6, s);
        s = dot2f(bc(vb.w), q7, s);

        s += __shfl_xor(s, 1);
        s += __shfl_xor(s, 2);     // 4-lane group holds full dot

        acc += (kidx < KNEG) ? __expf(s) : 0.f;   // TEMP == 1
    }
    acc += __shfl_xor(acc, 4);
    acc += __shfl_xor(acc, 8);
    acc += __shfl_xor(acc, 16);
    acc += __shfl_xor(acc, 32);

    if (l == 0) wpart[w] = log1pf(acc / pos[n]);   // log(p+neg)-log(p)
    __syncthreads();

    if (t == 0) {
        const float bsum = wpart[0] + wpart[1] + wpart[2] + wpart[3];
        __hip_atomic_store(&partials[blockIdx.x], bsum,
                           __ATOMIC_RELEASE, __HIP_MEMORY_SCOPE_AGENT);
        const int prev = __hip_atomic_fetch_add(cnt, 1, __ATOMIC_ACQ_REL,
                                                __HIP_MEMORY_SCOPE_AGENT);
        lastFlag = (prev == NBLK2 - 1);
    }
    __syncthreads();

    if (lastFlag) {                 // block-uniform -> syncthreads legal
        __threadfence();
        float a = 0.f;
        for (int i = t; i < NBLK2; i += 256)
            a += __hip_atomic_load(&partials[i], __ATOMIC_RELAXED,
                                   __HIP_MEMORY_SCOPE_AGENT);
        red[t] = a;
        __syncthreads();
        for (int off = 128; off > 0; off >>= 1) {
            if (t < off) red[t] += red[t + off];
            __syncthreads();
        }
        if (t == 0) out[0] = red[0] * (1.0f / (float)BHW);
    }
}

extern "C" void kernel_launch(void* const* d_in, const int* in_sizes, int n_in,
                              void* d_out, int out_size, void* d_ws, size_t ws_size,
                              hipStream_t stream)
{
    const float* x1  = (const float*)d_in[0];
    const float* x2  = (const float*)d_in[1];
    const int*   neg = (const int*)d_in[2];
    float* out = (float*)d_out;

    char* ws = (char*)d_ws;
    f16x2* xh       = (f16x2*)ws;                               // 25088*64 fp16 = 3.21 MB
    float* pos      = (float*)(ws + (size_t)BHW * DD * 2);      // 25088 f32
    float* partials = (float*)(ws + (size_t)BHW * DD * 2 + BHW * 4);
    int*   cnt      = (int*)  (ws + (size_t)BHW * DD * 2 + BHW * 4 + NBLK2 * 4);

    hipMemsetAsync(cnt, 0, sizeof(int), stream);
    k1_normalize<<<8 * 49, 256, 0, stream>>>(x1, x2, xh, pos);
    k2_negative<<<NBLK2, 256, 0, stream>>>(xh, neg, pos, partials, cnt, out);
}

// Round 4
// 103.973 us; speedup vs baseline: 3.0466x; 3.0466x over previous
//
#include <hip/hip_runtime.h>
#include <hip/hip_fp16.h>

#define BHW   25088
#define HW    3136
#define DD    64
#define KNEG  100
#define NBLK2 (BHW / 4)   // 6272 blocks, 4 waves (n's) per block

typedef _Float16 f16x2 __attribute__((ext_vector_type(2)));

#if __has_builtin(__builtin_amdgcn_fdot2)
#define HAVE_FDOT2 1
#else
#define HAVE_FDOT2 0
#endif

__device__ __forceinline__ float dot2f(f16x2 a, f16x2 b, float acc) {
#if HAVE_FDOT2
    return __builtin_amdgcn_fdot2(a, b, acc, false);   // v_dot2_f32_f16
#else
    return acc + (float)a.x * (float)b.x + (float)a.y * (float)b.y;
#endif
}

__device__ __forceinline__ f16x2 bc(float f) {
    union { float f; f16x2 h; } u; u.f = f; return u.h;
}

// ---------------------------------------------------------------------------
// Kernel 1: normalize x1 rows -> xh (fp16, row-major (n,64)), positive[n] in
// f32. LDS tile-transpose so d-major global reads and n-major writes are both
// coalesced. All 256 threads active in the norm/pos phase.
// ---------------------------------------------------------------------------
__global__ __launch_bounds__(256) void k1_normalize(
    const float* __restrict__ x1, const float* __restrict__ x2,
    f16x2* __restrict__ xh, float* __restrict__ pos)
{
    __shared__ float A[64][65];   // +1 pad: conflict-free column reads
    __shared__ float C[64][65];
    __shared__ float inv1[64];

    const int t   = threadIdx.x;
    const int col = t & 63;       // hw within tile
    const int qr  = t >> 6;       // wave id 0..3
    const int b    = blockIdx.x / 49;
    const int tile = blockIdx.x % 49;
    const int hw0  = tile * 64;

    const float* p1 = x1 + (size_t)b * DD * HW + hw0;
    const float* p2 = x2 + (size_t)b * DD * HW + hw0;

#pragma unroll
    for (int i = 0; i < 16; ++i) {
        const int row = i * 4 + qr;                  // d index
        A[row][col] = p1[(size_t)row * HW + col];    // coalesced 256B
        C[row][col] = p2[(size_t)row * HW + col];
    }
    __syncthreads();

    // phase 2: 256 threads = 64 rows x 4 d-chunks of 16
    const int l = t & 63;
    const int r = qr * 16 + (l & 15);   // row (hw) within tile
    const int c = l >> 4;               // d-chunk 0..3

    float na = 0.f, nc = 0.f;
#pragma unroll
    for (int j = 0; j < 16; ++j) {
        const int d = c * 16 + j;
        const float a = A[d][r], cc = C[d][r];
        na += a * a;
        nc += cc * cc;
    }
    na += __shfl_xor(na, 16); na += __shfl_xor(na, 32);
    nc += __shfl_xor(nc, 16); nc += __shfl_xor(nc, 32);
    const float r1 = 1.0f / fmaxf(sqrtf(na), 1e-12f);
    const float rc = 1.0f / fmaxf(sqrtf(nc), 1e-12f);
    const float scale = r1 * rc;

    float p = 0.f;
#pragma unroll
    for (int j = 0; j < 16; ++j) {
        const int d = c * 16 + j;
        p += __expf(A[d][r] * C[d][r] * scale);   // TEMP == 1
    }
    p += __shfl_xor(p, 16); p += __shfl_xor(p, 32);

    if (c == 0) {
        pos[b * HW + hw0 + r] = p;
        inv1[r] = r1;
    }
    __syncthreads();

    // phase 3: write fp16 table row-major. Half-wave (32 lanes) covers one
    // row's 32 half2 -> 128B contiguous per half-wave store.
    f16x2* outh = xh + (size_t)(b * HW + hw0) * 32;
    const int rowsub = t >> 5;    // 0..7
    const int cp = t & 31;        // half2 column 0..31
#pragma unroll
    for (int i = 0; i < 8; ++i) {
        const int nl = i * 8 + rowsub;
        const float s = inv1[nl];
        f16x2 v;
        v.x = (_Float16)(A[2 * cp][nl] * s);
        v.y = (_Float16)(A[2 * cp + 1][nl] * s);
        outh[(size_t)nl * 32 + cp] = v;
    }
}

// ---------------------------------------------------------------------------
// Kernel 2: negative[n] = sum_k exp(dot64(xh[n], xh[idx[n,k]])).
// One wave per n; 4 lanes per negative (g=l>>2), lane c=l&3 reads 32B of the
// gathered fp16 row (2x float4). Table is 3.2MB -> L2-resident per XCD.
// NO atomics / fences in this kernel (agent-scope atomics force per-XCD L2
// writeback+invalidate on gfx950 -> destroys the resident table; round-3
// regression). Plain store of block partial; separate k3 reduces.
// ---------------------------------------------------------------------------
__global__ __launch_bounds__(256) void k2_negative(
    const f16x2* __restrict__ xh, const int* __restrict__ neg_idx,
    const float* __restrict__ pos, float* __restrict__ partials)
{
    __shared__ float wpart[4];

    const int t = threadIdx.x;
    const int w = t >> 6;         // wave id 0..3
    const int l = t & 63;
    const int n = blockIdx.x * 4 + w;
    const int g = l >> 2;         // negative group 0..15
    const int c = l & 3;          // 32B slot within row

    const float4* gp = (const float4*)xh;   // 8 float4 per 128B row
    const int* idxp = neg_idx + (size_t)n * KNEG;

    // query fragment: halfs [c*16, c*16+16) of row n
    const size_t qb = (size_t)n * 8 + c * 2;
    const float4 qa = gp[qb], qv = gp[qb + 1];
    const f16x2 q0 = bc(qa.x), q1 = bc(qa.y), q2 = bc(qa.z), q3 = bc(qa.w);
    const f16x2 q4 = bc(qv.x), q5 = bc(qv.y), q6 = bc(qv.z), q7 = bc(qv.w);

    float acc = 0.f;
#pragma unroll
    for (int i = 0; i < 7; ++i) {
        const int kidx = i * 16 + g;
        const int kc   = kidx < KNEG ? kidx : (KNEG - 1);  // clamp (masked)
        const int row  = idxp[kc];
        const size_t base = (size_t)row * 8 + c * 2;
        const float4 va = gp[base], vb = gp[base + 1];

        float s = 0.f;
        s = dot2f(bc(va.x), q0, s);
        s = dot2f(bc(va.y), q1, s);
        s = dot2f(bc(va.z), q2, s);
        s = dot2f(bc(va.w), q3, s);
        s = dot2f(bc(vb.x), q4, s);
        s = dot2f(bc(vb.y), q5, s);
        s = dot2f(bc(vb.z), q6, s);
        s = dot2f(bc(vb.w), q7, s);

        s += __shfl_xor(s, 1);
        s += __shfl_xor(s, 2);     // 4-lane group holds full dot

        acc += (kidx < KNEG) ? __expf(s) : 0.f;   // TEMP == 1
    }
    acc += __shfl_xor(acc, 4);
    acc += __shfl_xor(acc, 8);
    acc += __shfl_xor(acc, 16);
    acc += __shfl_xor(acc, 32);

    if (l == 0) wpart[w] = log1pf(acc / pos[n]);   // log(p+neg)-log(p)
    __syncthreads();
    if (t == 0) {
        partials[blockIdx.x] = wpart[0] + wpart[1] + wpart[2] + wpart[3];
    }
}

// ---------------------------------------------------------------------------
// Kernel 3: reduce 6272 partials -> mean loss scalar.
// ---------------------------------------------------------------------------
__global__ __launch_bounds__(256) void k3_reduce(
    const float* __restrict__ partials, float* __restrict__ out)
{
    __shared__ float s[256];
    const int t = threadIdx.x;
    float a = 0.f;
    for (int i = t; i < NBLK2; i += 256) a += partials[i];
    s[t] = a;
    __syncthreads();
    for (int off = 128; off > 0; off >>= 1) {
        if (t < off) s[t] += s[t + off];
        __syncthreads();
    }
    if (t == 0) out[0] = s[0] * (1.0f / (float)BHW);
}

extern "C" void kernel_launch(void* const* d_in, const int* in_sizes, int n_in,
                              void* d_out, int out_size, void* d_ws, size_t ws_size,
                              hipStream_t stream)
{
    const float* x1  = (const float*)d_in[0];
    const float* x2  = (const float*)d_in[1];
    const int*   neg = (const int*)d_in[2];
    float* out = (float*)d_out;

    char* ws = (char*)d_ws;
    f16x2* xh       = (f16x2*)ws;                               // 25088*64 fp16 = 3.21 MB
    float* pos      = (float*)(ws + (size_t)BHW * DD * 2);      // 25088 f32
    float* partials = (float*)(ws + (size_t)BHW * DD * 2 + BHW * 4);

    k1_normalize<<<8 * 49, 256, 0, stream>>>(x1, x2, xh, pos);
    k2_negative<<<NBLK2, 256, 0, stream>>>(xh, neg, pos, partials);
    k3_reduce<<<1, 256, 0, stream>>>(partials, out);
}

// Round 5
// 99.892 us; speedup vs baseline: 3.1711x; 1.0409x over previous
//
#include <hip/hip_runtime.h>
#include <hip/hip_fp16.h>

#define BHW   25088
#define HW    3136
#define DD    64
#define KNEG  100
#define NBLK2 (BHW / 4)   // 6272 blocks, 4 waves (n's) per block

typedef float v2f __attribute__((ext_vector_type(2)));

#if __has_builtin(__builtin_amdgcn_cvt_pk_f32_fp8) && __has_builtin(__builtin_amdgcn_cvt_pk_fp8_f32)
#define HAVE_FP8CVT 1
#else
#define HAVE_FP8CVT 0
#endif

// ---- fp8 e4m3fn encode/decode (HW cvt on gfx950; SW fallback) -------------
__device__ __forceinline__ uint32_t enc4(float a, float b, float c, float d) {
#if HAVE_FP8CVT
    int u = __builtin_amdgcn_cvt_pk_fp8_f32(a, b, 0, false);
    u = __builtin_amdgcn_cvt_pk_fp8_f32(c, d, u, true);
    return (uint32_t)u;
#else
    auto enc1 = [](float x) -> uint32_t {
        float ax = fabsf(x);
        uint32_t s = (__float_as_uint(x) >> 31) << 7;
        if (ax < 0x1p-10f) return s;
        int e; float m = frexpf(ax, &e);          // ax = m*2^e, m in [0.5,1)
        if (e >= -5) {
            int mant = (int)rintf(m * 16.f);      // 8..16
            if (mant == 16) { mant = 8; e += 1; }
            if (e > 8) return s | 0x7e;           // clamp to max finite
            return s | ((uint32_t)(e + 6) << 3) | (uint32_t)(mant - 8);
        }
        int q = (int)rintf(ax * 512.f);           // denormal grid 2^-9
        if (q >= 8) return s | (1u << 3);
        return s | (uint32_t)q;
    };
    return enc1(a) | (enc1(b) << 8) | (enc1(c) << 16) | (enc1(d) << 24);
#endif
}

__device__ __forceinline__ void dec4(uint32_t u, float* f) {
#if HAVE_FP8CVT
    v2f p0 = __builtin_amdgcn_cvt_pk_f32_fp8((int)u, false);
    v2f p1 = __builtin_amdgcn_cvt_pk_f32_fp8((int)u, true);
    f[0] = p0.x; f[1] = p0.y; f[2] = p1.x; f[3] = p1.y;
#else
    for (int i = 0; i < 4; ++i) {
        uint32_t b = (u >> (8 * i)) & 0xff;
        uint32_t s = b >> 7, e = (b >> 3) & 15, m = b & 7;
        float v = e ? __uint_as_float(((e + 120u) << 23) | (m << 20))
                    : (float)m * 0x1p-9f;
        f[i] = s ? -v : v;
    }
#endif
}

// ---------------------------------------------------------------------------
// Kernel 1 (512 thr): normalize x1 rows -> xq (fp8 e4m3, row-major (n,64)),
// positive[n] in f32. LDS tile-transpose; 8 waves/block for latency hiding.
// ---------------------------------------------------------------------------
__global__ __launch_bounds__(512) void k1_normalize(
    const float* __restrict__ x1, const float* __restrict__ x2,
    uint32_t* __restrict__ xq, float* __restrict__ pos)
{
    __shared__ float A[64][65];   // +1 pad
    __shared__ float C[64][65];
    __shared__ float inv1[64];

    const int t   = threadIdx.x;
    const int col = t & 63;       // hw within tile
    const int qr  = t >> 6;       // wave id 0..7
    const int b    = blockIdx.x / 49;
    const int tile = blockIdx.x % 49;
    const int hw0  = tile * 64;

    const float* p1 = x1 + (size_t)b * DD * HW + hw0;
    const float* p2 = x2 + (size_t)b * DD * HW + hw0;

#pragma unroll
    for (int i = 0; i < 8; ++i) {
        const int row = i * 8 + qr;                  // d index
        A[row][col] = p1[(size_t)row * HW + col];    // coalesced 256B
        C[row][col] = p2[(size_t)row * HW + col];
    }
    __syncthreads();

    // phase 2: 512 threads = 64 rows x 8 d-chunks of 8 (8 lanes per row)
    const int l   = t & 63;
    const int r   = qr * 8 + (l >> 3);  // row (hw) within tile
    const int sub = l & 7;              // d-chunk 0..7

    float na = 0.f, nc = 0.f;
#pragma unroll
    for (int j = 0; j < 8; ++j) {
        const int d = sub * 8 + j;
        const float a = A[d][r], cc = C[d][r];
        na += a * a;
        nc += cc * cc;
    }
    na += __shfl_xor(na, 1); na += __shfl_xor(na, 2); na += __shfl_xor(na, 4);
    nc += __shfl_xor(nc, 1); nc += __shfl_xor(nc, 2); nc += __shfl_xor(nc, 4);
    const float r1 = 1.0f / fmaxf(sqrtf(na), 1e-12f);
    const float rc = 1.0f / fmaxf(sqrtf(nc), 1e-12f);
    const float scale = r1 * rc;

    float p = 0.f;
#pragma unroll
    for (int j = 0; j < 8; ++j) {
        const int d = sub * 8 + j;
        p += __expf(A[d][r] * C[d][r] * scale);   // TEMP == 1
    }
    p += __shfl_xor(p, 1); p += __shfl_xor(p, 2); p += __shfl_xor(p, 4);

    if (sub == 0) {
        pos[b * HW + hw0 + r] = p;
        inv1[r] = r1;
    }
    __syncthreads();

    // phase 3: write fp8 table row-major: 64 rows x 16 uint (4 fp8 each).
    uint32_t* outb = xq + (size_t)(b * HW + hw0) * 16;
    const int cp     = t & 15;    // uint index -> d = 4cp..4cp+3
    const int rowsel = t >> 4;    // 0..31
#pragma unroll
    for (int i = 0; i < 2; ++i) {
        const int nl = i * 32 + rowsel;
        const float s = inv1[nl];
        outb[(size_t)nl * 16 + cp] =
            enc4(A[4 * cp + 0][nl] * s, A[4 * cp + 1][nl] * s,
                 A[4 * cp + 2][nl] * s, A[4 * cp + 3][nl] * s);
    }
}

// ---------------------------------------------------------------------------
// Kernel 2: negative[n] = sum_k exp(dot64(xq[n], xq[idx[n,k]])).
// One wave per n; 4 lanes per negative (g=l>>2), lane c=l&3 reads one uint4
// (16 fp8 = quarter row). Each gathered row = exactly one 64B line fetched by
// one dwordx4. Table 1.6MB -> fully L2-resident per XCD. NO fences/atomics
// (round-3 lesson: agent-scope acq/rel flushes per-XCD L2).
// ---------------------------------------------------------------------------
__device__ __forceinline__ float neg_term(const uint4* __restrict__ gp,
                                          int row, int c,
                                          const float* __restrict__ qf)
{
    const uint4 v = gp[(size_t)row * 4 + c];
    float kf[16];
    dec4(v.x, kf + 0); dec4(v.y, kf + 4);
    dec4(v.z, kf + 8); dec4(v.w, kf + 12);
    float s0 = 0.f, s1 = 0.f;
#pragma unroll
    for (int j = 0; j < 8; ++j) {
        s0 = fmaf(kf[2 * j + 0], qf[2 * j + 0], s0);
        s1 = fmaf(kf[2 * j + 1], qf[2 * j + 1], s1);
    }
    float s = s0 + s1;
    s += __shfl_xor(s, 1);
    s += __shfl_xor(s, 2);     // 4-lane group holds full dot
    return __expf(s);          // TEMP == 1
}

__global__ __launch_bounds__(256) void k2_negative(
    const uint32_t* __restrict__ xq, const int* __restrict__ neg_idx,
    const float* __restrict__ pos, float* __restrict__ partials)
{
    __shared__ float wpart[4];

    const int t = threadIdx.x;
    const int w = t >> 6;         // wave id 0..3
    const int l = t & 63;
    const int n = blockIdx.x * 4 + w;
    const int g = l >> 2;         // negative group 0..15
    const int c = l & 3;          // 16B slot within 64B row

    const uint4* gp = (const uint4*)xq;   // 4 x uint4 per row
    const int* idxp = neg_idx + (size_t)n * KNEG;

    // query fragment: d in [16c, 16c+16) of row n, decoded once to f32
    const uint4 qw = gp[(size_t)n * 4 + c];
    float qf[16];
    dec4(qw.x, qf + 0); dec4(qw.y, qf + 4);
    dec4(qw.z, qf + 8); dec4(qw.w, qf + 12);

    float acc = 0.f;
#pragma unroll
    for (int i = 0; i < 6; ++i) {
        acc += neg_term(gp, idxp[i * 16 + g], c, qf);   // k = i*16+g
    }
    if (g < 4) {                                        // k = 96..99 (group-uniform)
        acc += neg_term(gp, idxp[96 + g], c, qf);
    }
    // lanes within a group hold identical acc; butterfly across 16 groups
    acc += __shfl_xor(acc, 4);
    acc += __shfl_xor(acc, 8);
    acc += __shfl_xor(acc, 16);
    acc += __shfl_xor(acc, 32);

    if (l == 0) wpart[w] = log1pf(acc / pos[n]);   // log(p+neg)-log(p)
    __syncthreads();
    if (t == 0) {
        partials[blockIdx.x] = wpart[0] + wpart[1] + wpart[2] + wpart[3];
    }
}

// ---------------------------------------------------------------------------
// Kernel 3: reduce 6272 partials -> mean loss scalar.
// ---------------------------------------------------------------------------
__global__ __launch_bounds__(256) void k3_reduce(
    const float* __restrict__ partials, float* __restrict__ out)
{
    __shared__ float s[256];
    const int t = threadIdx.x;
    float a = 0.f;
    for (int i = t; i < NBLK2; i += 256) a += partials[i];
    s[t] = a;
    __syncthreads();
    for (int off = 128; off > 0; off >>= 1) {
        if (t < off) s[t] += s[t + off];
        __syncthreads();
    }
    if (t == 0) out[0] = s[0] * (1.0f / (float)BHW);
}

extern "C" void kernel_launch(void* const* d_in, const int* in_sizes, int n_in,
                              void* d_out, int out_size, void* d_ws, size_t ws_size,
                              hipStream_t stream)
{
    const float* x1  = (const float*)d_in[0];
    const float* x2  = (const float*)d_in[1];
    const int*   neg = (const int*)d_in[2];
    float* out = (float*)d_out;

    char* ws = (char*)d_ws;
    uint32_t* xq    = (uint32_t*)ws;                            // 25088*64 fp8 = 1.61 MB
    float* pos      = (float*)(ws + (size_t)BHW * DD);          // 25088 f32
    float* partials = (float*)(ws + (size_t)BHW * DD + BHW * 4);

    k1_normalize<<<8 * 49, 512, 0, stream>>>(x1, x2, xq, pos);
    k2_negative<<<NBLK2, 256, 0, stream>>>(xq, neg, pos, partials);
    k3_reduce<<<1, 256, 0, stream>>>(partials, out);
}